// Round 1
// baseline (2693.385 us; speedup 1.0000x reference)
//
#include <hip/hip_runtime.h>
#include <math.h>

// ---------------------------------------------------------------------------
// RSSM, Round 4: register M-blocking 16 -> 32 rows/wave on the three
// traffic-dominant GEMMs (embed_state, gru, pp).  Blocks regrouped as
// {same weight-column nt, 4 row-blocks} so B-fragment reads are
// L1-coincident within a CU and nt-panels pin to one XCD's L2
// (b, b+64, b+128, b+192 all map to the same XCD under %8 round-robin).
// B-traffic per step: gru 400->200 MB, pp 190->95 MB. k_head unchanged.
// ---------------------------------------------------------------------------

typedef __attribute__((ext_vector_type(8))) short bf16x8;
typedef __attribute__((ext_vector_type(4))) float f32x4;

#define MFMA(a, b, c) __builtin_amdgcn_mfma_f32_16x16x32_bf16(a, b, c, 0, 0, 0)

__device__ __forceinline__ short f2bf(float f) {
    unsigned u = __float_as_uint(f);
    u += 0x7FFF + ((u >> 16) & 1);   // RNE
    return (short)(u >> 16);
}
__device__ __forceinline__ float sigmoidf_(float x) { return 1.f / (1.f + expf(-x)); }
__device__ __forceinline__ float softplusf_(float x) {
    return fmaxf(x, 0.f) + log1pf(expf(-fabsf(x)));
}
__device__ __forceinline__ f32x4 zero4() { f32x4 v = {0.f, 0.f, 0.f, 0.f}; return v; }

// B-frag pre-swizzle (one wave per 16n x 32k tile):
// out[((nt*KT+kt)*64 + lane)*8 + j] = bf16(W[(kt*32+(lane>>4)*8+j)*N + nt*16 + (lane&15)])
__global__ __launch_bounds__(256) void k_swizzle(const float* __restrict__ W,
                                                 short* __restrict__ out,
                                                 int KT, int N)
{
    int gw = blockIdx.x * 4 + (threadIdx.x >> 6);
    int lane = threadIdx.x & 63;
    int nt = gw / KT, kt = gw % KT;
    const float* src = W + (size_t)(kt * 32 + (lane >> 4) * 8) * N + nt * 16 + (lane & 15);
    short tmp[8];
#pragma unroll
    for (int j = 0; j < 8; ++j) tmp[j] = f2bf(src[(size_t)j * N]);
    *(bf16x8*)(out + (((size_t)gw * 64 + lane) << 3)) = *(const bf16x8*)tmp;
}

// obs fp32 [32*512*1024] -> bf16
__global__ __launch_bounds__(256) void k_obs2bf(const float* __restrict__ obs,
                                                short* __restrict__ out)
{
    size_t i = ((size_t)blockIdx.x * 256 + threadIdx.x) * 8;
    short tmp[8];
#pragma unroll
    for (int j = 0; j < 8; ++j) tmp[j] = f2bf(obs[i + j]);
    *(bf16x8*)(out + i) = *(const bf16x8*)tmp;
}

// init stateCat[512][512] = [prev|prev] bf16, belief buf bf16
__global__ __launch_bounds__(256) void k_init(const float* __restrict__ prev_state,
                                              const float* __restrict__ prev_belief,
                                              short* __restrict__ stateCat,
                                              short* __restrict__ belief1)
{
    int i = blockIdx.x * 256 + threadIdx.x;
    if (i < 262144) {
        int m = i >> 9, c = i & 511;
        stateCat[i] = f2bf(prev_state[m * 256 + (c & 255)]);
    } else {
        int j = i - 262144;
        belief1[j] = f2bf(prev_belief[j]);
    }
}

__device__ __forceinline__ bf16x8 loadA16(const short* A, int m0, int kelem, int strideElems, int lane) {
    return *(const bf16x8*)(A + (size_t)(m0 + (lane & 15)) * strideElems + kelem + ((lane >> 4) << 3));
}
__device__ __forceinline__ bf16x8 loadB16(const short* Bsw, size_t tileIdx, int lane) {
    return *(const bf16x8*)(Bsw + ((tileIdx * 64 + lane) << 3));
}

// ---------------------------------------------------------------------------
// embed_state: hidden = relu(stateCat @ w_es + b).  M=512,K=512,N=1024.
// 256 blocks: block = {nt, 4 row-blocks}; wave = 32 rows x 16 cols.
// ---------------------------------------------------------------------------
__global__ __launch_bounds__(256) void k_embed_state(
    const short* __restrict__ A, const short* __restrict__ Bsw,
    const float* __restrict__ bias, short* __restrict__ outBf)
{
    int wid = threadIdx.x >> 6;
    int lane = threadIdx.x & 63;
    int nt = blockIdx.x & 63, mb = blockIdx.x >> 6;
    int m0 = (mb * 4 + wid) * 32;
    f32x4 acc0 = zero4(), acc1 = zero4();
#pragma unroll 4
    for (int kt = 0; kt < 16; ++kt) {
        bf16x8 a0 = loadA16(A, m0,      kt * 32, 512, lane);
        bf16x8 a1 = loadA16(A, m0 + 16, kt * 32, 512, lane);
        bf16x8 b  = loadB16(Bsw, (size_t)nt * 16 + kt, lane);
        acc0 = MFMA(a0, b, acc0);
        acc1 = MFMA(a1, b, acc1);
    }
    int q = lane >> 4, cl = lane & 15;
    int n = nt * 16 + cl;
    float bn = bias[n];
#pragma unroll
    for (int i = 0; i < 4; ++i) {
        int m = m0 + q * 4 + i;
        outBf[(size_t)m * 1024 + n]        = f2bf(fmaxf(acc0[i] + bn, 0.f));
        outBf[(size_t)(m + 16) * 1024 + n] = f2bf(fmaxf(acc1[i] + bn, 0.f));
    }
}

// ---------------------------------------------------------------------------
// GRU: 256 blocks: block = {nt of 16 belief cols, 4 row-blocks};
// wave = 32 rows x 16 cols x 3 gates.  r/z accumulate over K=2048.
// sw_ih/sw_hh: N=3072 -> 192 ntile16, KT=32; gate g tile base = g*64 + nt.
// ---------------------------------------------------------------------------
__global__ __launch_bounds__(256) void k_gru(
    const short* __restrict__ Hbf, const short* __restrict__ Pbf,
    const float* __restrict__ Pf32,
    const short* __restrict__ sw_ih, const short* __restrict__ sw_hh,
    const float* __restrict__ b_ih, const float* __restrict__ b_hh,
    float* __restrict__ belF32, short* __restrict__ belBf)
{
    int wid = threadIdx.x >> 6;
    int lane = threadIdx.x & 63;
    int nt = blockIdx.x & 63, mb = blockIdx.x >> 6;
    int m0 = (mb * 4 + wid) * 32;
    f32x4 r0 = zero4(), r1 = zero4(), z0 = zero4(), z1 = zero4();
    f32x4 ni0 = zero4(), ni1 = zero4(), nh0 = zero4(), nh1 = zero4();

#pragma unroll 4
    for (int kt = 0; kt < 32; ++kt) {   // phase 0: hidden @ w_ih
        bf16x8 a0 = loadA16(Hbf, m0,      kt * 32, 1024, lane);
        bf16x8 a1 = loadA16(Hbf, m0 + 16, kt * 32, 1024, lane);
        bf16x8 br = loadB16(sw_ih, (size_t)(0 * 64 + nt) * 32 + kt, lane);
        bf16x8 bz = loadB16(sw_ih, (size_t)(1 * 64 + nt) * 32 + kt, lane);
        bf16x8 bn = loadB16(sw_ih, (size_t)(2 * 64 + nt) * 32 + kt, lane);
        r0 = MFMA(a0, br, r0);   r1 = MFMA(a1, br, r1);
        z0 = MFMA(a0, bz, z0);   z1 = MFMA(a1, bz, z1);
        ni0 = MFMA(a0, bn, ni0); ni1 = MFMA(a1, bn, ni1);
    }
#pragma unroll 4
    for (int kt = 0; kt < 32; ++kt) {   // phase 1: beliefPrev @ w_hh
        bf16x8 a0 = loadA16(Pbf, m0,      kt * 32, 1024, lane);
        bf16x8 a1 = loadA16(Pbf, m0 + 16, kt * 32, 1024, lane);
        bf16x8 br = loadB16(sw_hh, (size_t)(0 * 64 + nt) * 32 + kt, lane);
        bf16x8 bz = loadB16(sw_hh, (size_t)(1 * 64 + nt) * 32 + kt, lane);
        bf16x8 bn = loadB16(sw_hh, (size_t)(2 * 64 + nt) * 32 + kt, lane);
        r0 = MFMA(a0, br, r0);   r1 = MFMA(a1, br, r1);
        z0 = MFMA(a0, bz, z0);   z1 = MFMA(a1, bz, z1);
        nh0 = MFMA(a0, bn, nh0); nh1 = MFMA(a1, bn, nh1);
    }

    int q = lane >> 4, cl = lane & 15;
    int n = nt * 16 + cl;
    float bihr = b_ih[n] + b_hh[n];
    float bihz = b_ih[1024 + n] + b_hh[1024 + n];
    float bin = b_ih[2048 + n], bhn = b_hh[2048 + n];
#pragma unroll
    for (int f = 0; f < 2; ++f) {
#pragma unroll
        for (int i = 0; i < 4; ++i) {
            int m = m0 + f * 16 + q * 4 + i;
            float rv = f ? r1[i] : r0[i];
            float zv = f ? z1[i] : z0[i];
            float niv = f ? ni1[i] : ni0[i];
            float nhv = f ? nh1[i] : nh0[i];
            float rr = sigmoidf_(rv + bihr);
            float zz = sigmoidf_(zv + bihz);
            float ng = tanhf(niv + bin + rr * (nhv + bhn));
            float h = Pf32[(size_t)m * 1024 + n];
            float v = (1.f - zz) * ng + zz * h;
            belF32[(size_t)m * 1024 + n] = v;
            belBf[(size_t)m * 1024 + n] = f2bf(v);
        }
    }
}

// ---------------------------------------------------------------------------
// fused posterior+prior embeds.  blocks 0..255: hp (K=2048: belief|obsBf);
// blocks 256..511: hq (K=1024 + rank-6 pose epilogue).  Wave = 32x16.
// ---------------------------------------------------------------------------
__global__ __launch_bounds__(256) void k_pp(
    const short* __restrict__ Bel, const short* __restrict__ ObsBf,
    const float* __restrict__ Pose,
    const short* __restrict__ sw_ebpo, const short* __restrict__ sw_ebpr,
    const float* __restrict__ Wf_ebpr,
    const float* __restrict__ b_ebpo, const float* __restrict__ b_ebpr,
    short* __restrict__ hpBf, short* __restrict__ hqBf)
{
    int wid = threadIdx.x >> 6;
    int lane = threadIdx.x & 63;
    int q = lane >> 4, cl = lane & 15;
    int b = blockIdx.x;
    if (b < 256) {
        int nt = b & 63, mb = b >> 6;
        int m0 = (mb * 4 + wid) * 32;
        f32x4 acc0 = zero4(), acc1 = zero4();
#pragma unroll 4
        for (int kt = 0; kt < 32; ++kt) {
            bf16x8 a0 = loadA16(Bel, m0,      kt * 32, 1024, lane);
            bf16x8 a1 = loadA16(Bel, m0 + 16, kt * 32, 1024, lane);
            bf16x8 bb = loadB16(sw_ebpo, (size_t)nt * 64 + kt, lane);
            acc0 = MFMA(a0, bb, acc0);
            acc1 = MFMA(a1, bb, acc1);
        }
#pragma unroll 4
        for (int kt = 32; kt < 64; ++kt) {
            bf16x8 a0 = loadA16(ObsBf, m0,      (kt - 32) * 32, 1024, lane);
            bf16x8 a1 = loadA16(ObsBf, m0 + 16, (kt - 32) * 32, 1024, lane);
            bf16x8 bb = loadB16(sw_ebpo, (size_t)nt * 64 + kt, lane);
            acc0 = MFMA(a0, bb, acc0);
            acc1 = MFMA(a1, bb, acc1);
        }
        int n = nt * 16 + cl;
        float bn = b_ebpo[n];
#pragma unroll
        for (int i = 0; i < 4; ++i) {
            int m = m0 + q * 4 + i;
            hpBf[(size_t)m * 1024 + n]        = f2bf(fmaxf(acc0[i] + bn, 0.f));
            hpBf[(size_t)(m + 16) * 1024 + n] = f2bf(fmaxf(acc1[i] + bn, 0.f));
        }
    } else {
        int b2 = b - 256;
        int nt = b2 & 63, mb = b2 >> 6;
        int m0 = (mb * 4 + wid) * 32;
        f32x4 acc0 = zero4(), acc1 = zero4();
#pragma unroll 4
        for (int kt = 0; kt < 32; ++kt) {
            bf16x8 a0 = loadA16(Bel, m0,      kt * 32, 1024, lane);
            bf16x8 a1 = loadA16(Bel, m0 + 16, kt * 32, 1024, lane);
            bf16x8 bb = loadB16(sw_ebpr, (size_t)nt * 32 + kt, lane);
            acc0 = MFMA(a0, bb, acc0);
            acc1 = MFMA(a1, bb, acc1);
        }
        int n = nt * 16 + cl;
        float bn = b_ebpr[n];
#pragma unroll
        for (int f = 0; f < 2; ++f) {
#pragma unroll
            for (int i = 0; i < 4; ++i) {
                int m = m0 + f * 16 + q * 4 + i;
                float v = (f ? acc1[i] : acc0[i]) + bn;
#pragma unroll
                for (int p = 0; p < 6; ++p)
                    v += Pose[(size_t)m * 6 + p] * Wf_ebpr[(size_t)(1024 + p) * 1024 + n];
                hqBf[(size_t)m * 1024 + n] = f2bf(fmaxf(v, 0.f));
            }
        }
    }
}

// ---------------------------------------------------------------------------
// head: 1024 waves: br(2) x mt(32) x ct(16 of 16 cols); mean+std paired.
// ---------------------------------------------------------------------------
__global__ __launch_bounds__(256) void k_head(
    const short* __restrict__ Hp, const short* __restrict__ Hq,
    const short* __restrict__ sw_spo, const short* __restrict__ sw_spr,
    const float* __restrict__ b_spo, const float* __restrict__ b_spr,
    const float* __restrict__ nPost, const float* __restrict__ nPri,
    float* __restrict__ pM, float* __restrict__ pS, float* __restrict__ pSt,
    float* __restrict__ qM, float* __restrict__ qS, float* __restrict__ qSt,
    short* __restrict__ stateCat)
{
    int gw = blockIdx.x * 4 + (threadIdx.x >> 6);
    int lane = threadIdx.x & 63;
    int br = gw >> 9, rem = gw & 511;
    int mt = rem >> 4, ct = rem & 15;
    int m0 = mt * 16;
    const short* A = br ? Hq : Hp;
    const short* Bsw = br ? sw_spr : sw_spo;
    const float* bias = br ? b_spr : b_spo;
    const float* noise = br ? nPri : nPost;
    float* mO = br ? qM : pM;
    float* sO = br ? qS : pS;
    float* stO = br ? qSt : pSt;
    int catOff = br ? 256 : 0;
    f32x4 ma = zero4(), sa = zero4();
#pragma unroll 4
    for (int kt = 0; kt < 32; ++kt) {
        bf16x8 a = loadA16(A, m0, kt * 32, 1024, lane);
        bf16x8 bm = loadB16(Bsw, (size_t)ct * 32 + kt, lane);
        bf16x8 bs = loadB16(Bsw, (size_t)(16 + ct) * 32 + kt, lane);
        ma = MFMA(a, bm, ma);
        sa = MFMA(a, bs, sa);
    }
    int q = lane >> 4, cl = lane & 15;
#pragma unroll
    for (int i = 0; i < 4; ++i) {
        int m = m0 + q * 4 + i;
        int c = ct * 16 + cl;
        float mean = ma[i] + bias[c];
        float sd = softplusf_(sa[i] + bias[c + 256]) + 0.1f;
        float st = mean + sd * noise[(size_t)m * 256 + c];
        mO[(size_t)m * 256 + c] = mean;
        sO[(size_t)m * 256 + c] = sd;
        stO[(size_t)m * 256 + c] = st;
        stateCat[(size_t)m * 512 + catOff + c] = f2bf(st);
    }
}

// ---------------------------------------------------------------------------
extern "C" void kernel_launch(void* const* d_in, const int* in_sizes, int n_in,
                              void* d_out, int out_size, void* d_ws, size_t ws_size,
                              hipStream_t stream)
{
    const float* prev_state  = (const float*)d_in[0];
    const float* prev_belief = (const float*)d_in[1];
    const float* poses       = (const float*)d_in[2];
    const float* obs         = (const float*)d_in[3];
    const float* post_noise  = (const float*)d_in[4];
    const float* prior_noise = (const float*)d_in[5];
    const float* w_es   = (const float*)d_in[6];
    const float* b_es   = (const float*)d_in[7];
    const float* w_ih   = (const float*)d_in[8];
    const float* w_hh   = (const float*)d_in[9];
    const float* b_ih   = (const float*)d_in[10];
    const float* b_hh   = (const float*)d_in[11];
    const float* w_ebpo = (const float*)d_in[12];
    const float* b_ebpo = (const float*)d_in[13];
    const float* w_spo  = (const float*)d_in[14];
    const float* b_spo  = (const float*)d_in[15];
    const float* w_ebpr = (const float*)d_in[16];
    const float* b_ebpr = (const float*)d_in[17];
    const float* w_spr  = (const float*)d_in[18];
    const float* b_spr  = (const float*)d_in[19];

    float* out = (float*)d_out;
    float* beliefs    = out;
    float* priStates  = out + 16777216;
    float* priMeans   = out + 20971520;
    float* priStds    = out + 25165824;
    float* postStates = out + 29360128;
    float* postMeans  = out + 33554432;
    float* postStds   = out + 37748736;

    short* ws = (short*)d_ws;
    size_t o = 0;
    short* sw_es   = ws + o; o += (size_t)512 * 1024;
    short* sw_ih   = ws + o; o += (size_t)1024 * 3072;
    short* sw_hh   = ws + o; o += (size_t)1024 * 3072;
    short* sw_ebpo = ws + o; o += (size_t)2048 * 1024;
    short* sw_ebpr = ws + o; o += (size_t)1024 * 1024;
    short* sw_spo  = ws + o; o += (size_t)1024 * 512;
    short* sw_spr  = ws + o; o += (size_t)1024 * 512;
    short* hidden  = ws + o; o += (size_t)512 * 1024;
    short* belBuf0 = ws + o; o += (size_t)512 * 1024;
    short* belBuf1 = ws + o; o += (size_t)512 * 1024;
    short* hpBuf   = ws + o; o += (size_t)512 * 1024;
    short* hqBuf   = ws + o; o += (size_t)512 * 1024;
    short* stateCat = ws + o; o += (size_t)512 * 512;
    short* obsBf   = ws + o; o += (size_t)32 * 512 * 1024;

    // ---- pre-pass ----
    k_swizzle<<<dim3(256),  dim3(256), 0, stream>>>(w_es,   sw_es,   16, 1024);
    k_swizzle<<<dim3(1536), dim3(256), 0, stream>>>(w_ih,   sw_ih,   32, 3072);
    k_swizzle<<<dim3(1536), dim3(256), 0, stream>>>(w_hh,   sw_hh,   32, 3072);
    k_swizzle<<<dim3(1024), dim3(256), 0, stream>>>(w_ebpo, sw_ebpo, 64, 1024);
    k_swizzle<<<dim3(512),  dim3(256), 0, stream>>>(w_ebpr, sw_ebpr, 32, 1024);
    k_swizzle<<<dim3(256),  dim3(256), 0, stream>>>(w_spo,  sw_spo,  32, 512);
    k_swizzle<<<dim3(256),  dim3(256), 0, stream>>>(w_spr,  sw_spr,  32, 512);
    k_obs2bf<<<dim3(8192), dim3(256), 0, stream>>>(obs, obsBf);
    k_init<<<dim3(3072), dim3(256), 0, stream>>>(prev_state, prev_belief, stateCat, belBuf1);

    for (int t = 0; t < 32; ++t) {
        short* belPrevBf = (t & 1) ? belBuf0 : belBuf1;
        short* belCurBf  = (t & 1) ? belBuf1 : belBuf0;
        const float* belPrevF = t ? (beliefs + (size_t)(t - 1) * 524288) : prev_belief;
        float* belT = beliefs + (size_t)t * 524288;

        k_embed_state<<<dim3(256), dim3(256), 0, stream>>>(stateCat, sw_es, b_es, hidden);
        k_gru<<<dim3(256), dim3(256), 0, stream>>>(hidden, belPrevBf, belPrevF,
                                                   sw_ih, sw_hh, b_ih, b_hh, belT, belCurBf);
        k_pp<<<dim3(512), dim3(256), 0, stream>>>(belCurBf, obsBf + (size_t)t * 524288,
                                                  poses + (size_t)t * 3072,
                                                  sw_ebpo, sw_ebpr, w_ebpr,
                                                  b_ebpo, b_ebpr, hpBuf, hqBuf);
        k_head<<<dim3(256), dim3(256), 0, stream>>>(hpBuf, hqBuf, sw_spo, sw_spr, b_spo, b_spr,
                                                    post_noise + (size_t)t * 131072,
                                                    prior_noise + (size_t)t * 131072,
                                                    postMeans + (size_t)t * 131072,
                                                    postStds + (size_t)t * 131072,
                                                    postStates + (size_t)t * 131072,
                                                    priMeans + (size_t)t * 131072,
                                                    priStds + (size_t)t * 131072,
                                                    priStates + (size_t)t * 131072,
                                                    stateCat);
    }
}